// Round 3
// baseline (27781.009 us; speedup 1.0000x reference)
//
#include <hip/hip_runtime.h>
#include <math.h>

#define BDIM 256
#define DDIM 2048
constexpr float DT    = 0.1f;
constexpr float TOL   = 0.01f;
constexpr int   NSTEP = 50;      // int(5.0 / 0.1)
constexpr float EPS_  = 1e-8f;

typedef __attribute__((ext_vector_type(8))) short short8;   // 8 bf16 (MFMA A/B frag)
typedef __attribute__((ext_vector_type(4))) float f32x4;    // MFMA C/D frag

__device__ __forceinline__ ushort f2bf(float f) {           // fp32 -> bf16 RNE
    unsigned u = __float_as_uint(f);
    return (ushort)((u + 0x7fffu + ((u >> 16) & 1u)) >> 16);
}
__device__ __forceinline__ float bf2f(ushort h) { return __uint_as_float(((unsigned)h) << 16); }

#define GLOAD_LDS16(g, l) __builtin_amdgcn_global_load_lds( \
    (const __attribute__((address_space(1))) void*)(g),      \
    (__attribute__((address_space(3))) void*)(l), 16, 0, 0)

// ---------------------------------------------------------------------------
// One-time prepack: W -> bf16 hi/lo row-major (NT B operand: W[n][k] k-contig)
// ---------------------------------------------------------------------------
__global__ __launch_bounds__(256)
void prep_w_k(const float* __restrict__ W, ushort* __restrict__ Wh, ushort* __restrict__ Wl)
{
    const size_t i = ((size_t)blockIdx.x * 256 + threadIdx.x) * 4;
    const float4 v = *(const float4*)(W + i);
    ushort4 h, l;
    h.x = f2bf(v.x); l.x = f2bf(v.x - bf2f(h.x));
    h.y = f2bf(v.y); l.y = f2bf(v.y - bf2f(h.y));
    h.z = f2bf(v.z); l.z = f2bf(v.z - bf2f(h.z));
    h.w = f2bf(v.w); l.w = f2bf(v.w - bf2f(h.w));
    *(ushort4*)(Wh + i) = h;
    *(ushort4*)(Wl + i) = l;
}

// One-time prepack: W^T -> bf16 hi/lo (NN B operand: Wt[n][k]=W[k][n] k-contig)
__global__ __launch_bounds__(256)
void prep_wt_k(const float* __restrict__ W, ushort* __restrict__ Wth, ushort* __restrict__ Wtl)
{
    __shared__ float T[64][65];
    const int t = threadIdx.x;
    const int k0 = blockIdx.y * 64, n0 = blockIdx.x * 64;
    const int r = t >> 2, c4 = (t & 3) * 16;
    const float* src = W + (size_t)(k0 + r) * DDIM + n0 + c4;
    #pragma unroll
    for (int j = 0; j < 4; ++j) {
        const float4 v = *(const float4*)(src + j * 4);
        T[r][c4 + j*4 + 0] = v.x; T[r][c4 + j*4 + 1] = v.y;
        T[r][c4 + j*4 + 2] = v.z; T[r][c4 + j*4 + 3] = v.w;
    }
    __syncthreads();
    ushort hb[16], lb[16];
    #pragma unroll
    for (int j = 0; j < 16; ++j) {
        const float v = T[c4 + j][r];
        hb[j] = f2bf(v); lb[j] = f2bf(v - bf2f(hb[j]));
    }
    ushort* oh = Wth + (size_t)(n0 + r) * DDIM + k0 + c4;
    ushort* ol = Wtl + (size_t)(n0 + r) * DDIM + k0 + c4;
    #pragma unroll
    for (int q = 0; q < 4; ++q) {
        *(ushort4*)(oh + q*4) = make_ushort4(hb[q*4], hb[q*4+1], hb[q*4+2], hb[q*4+3]);
        *(ushort4*)(ol + q*4) = make_ushort4(lb[q*4], lb[q*4+1], lb[q*4+2], lb[q*4+3]);
    }
}

// init: x = x0; As = split(x0); zero csum/maxu/done
__global__ __launch_bounds__(256)
void init3_k(const float* __restrict__ x0, float* __restrict__ x,
             ushort* __restrict__ Ash, ushort* __restrict__ Asl,
             float* __restrict__ csum, unsigned* __restrict__ maxu, int* __restrict__ done)
{
    const size_t i = ((size_t)blockIdx.x * 256 + threadIdx.x) * 4;
    const float4 v = *(const float4*)(x0 + i);
    *(float4*)(x + i) = v;
    ushort4 h, l;
    h.x = f2bf(v.x); l.x = f2bf(v.x - bf2f(h.x));
    h.y = f2bf(v.y); l.y = f2bf(v.y - bf2f(h.y));
    h.z = f2bf(v.z); l.z = f2bf(v.z - bf2f(h.z));
    h.w = f2bf(v.w); l.w = f2bf(v.w - bf2f(h.w));
    *(ushort4*)(Ash + i) = h;
    *(ushort4*)(Asl + i) = l;
    if (blockIdx.x == 0) {
        for (int j = threadIdx.x; j < 1024; j += 256) csum[j] = 0.f;
        if (threadIdx.x == 0) { *maxu = 0u; *done = 0; }
    }
}

// ---------------------------------------------------------------------------
// Fused split-bf16 MFMA GEMM v3. Tile 32x64, BK=64, 512 thr (8 waves),
// grid (32,8)=256 blocks. Two 4-wave teams split K (1024 each), LDS-reduced.
// All operands pre-split bf16 hi/lo in global; K-loop is DMA+ds_read+MFMA only.
// XOR swizzle ((rc&7)<<3 in k-shorts) on both staging source and frag reads.
// MODE 0: NN  z=A@Wt; epi: h=tanh(z+b), store P=split(h(1-h^2)), csum+=h^2
// MODE 1: NT  kv=-cf*(P@W^T); epi: S=kv, max|kv|, As=split(x+0.5DT*kv)
// MODE 2: NT  epi: S+=2kv, As=split(x+0.5DT*kv)
// MODE 3: NT  epi: S+=2kv, As=split(x+DT*kv)
// MODE 4: NT  epi: x+=DT/6*(S+kv), As=split(x_new)
// NT modes zero cs_next (block 0,0).
// ---------------------------------------------------------------------------
template<int MODE>
__global__ __launch_bounds__(512, 1)
void hop3_mm(const ushort* __restrict__ Ahg, const ushort* __restrict__ Alg,
             const ushort* __restrict__ Bhg, const ushort* __restrict__ Blg,
             const float* __restrict__ bias,
             ushort* __restrict__ Oh, ushort* __restrict__ Ol,
             float* __restrict__ cs_cur, float* __restrict__ cs_next,
             const float* __restrict__ xin, float* __restrict__ xio,
             float* __restrict__ S,
             ushort* __restrict__ Ash, ushort* __restrict__ Asl,
             float cmul, unsigned* __restrict__ maxu, const int* __restrict__ done)
{
    constexpr bool NN = (MODE == 0);
    if (*done) return;

    // [team][dbuf]: Ah 2048 | Al 2048 | Bh 4096 | Bl 4096 shorts = 24KB; total 96KB
    __shared__ __align__(16) ushort lds[2][2][12288];

    const int t = threadIdx.x, lane = t & 63, wid = t >> 6;
    const int team = wid >> 2, w4 = wid & 3;
    const int wr = w4 >> 1, wc = w4 & 1;
    const int row0 = blockIdx.y * 32, col0 = blockIdx.x * 64;

    if (!NN && blockIdx.x == 0 && blockIdx.y == 0 && t < 256) cs_next[t] = 0.f;

    // staging: per team 24 x 1KB DMA; wave w4 issues q = w4 + {0,4,...,20}
    auto stage = [&](int it, int db) {
        ushort* tb = &lds[team][db][0];
        const int kg = team * 1024 + it * 64;
        #pragma unroll
        for (int j = 0; j < 6; ++j) {
            const int q = w4 + j * 4;                  // 0..23
            const ushort* srcb;
            int rc, base0;
            if (q < 8) {        // A region: rows 0..31
                srcb = (q < 4) ? Ahg : Alg;
                rc = (q & 3) * 8 + (lane >> 3);
                base0 = row0;
            } else {            // B region: cols 0..63
                const int qq = q - 8;
                srcb = (qq < 8) ? Bhg : Blg;
                rc = (qq & 7) * 8 + (lane >> 3);
                base0 = col0;
            }
            const int kk = ((lane & 7) * 8) ^ ((rc & 7) << 3);   // pre-swizzled source
            GLOAD_LDS16(srcb + (size_t)(base0 + rc) * DDIM + kg + kk, tb + q * 512);
        }
    };

    f32x4 acc0 = {0.f, 0.f, 0.f, 0.f};
    f32x4 acc1 = {0.f, 0.f, 0.f, 0.f};

    stage(0, 0);
    __syncthreads();

    const int fr = lane & 15;
    const int swz = (fr & 7) << 3;
    const int arow = wr * 16 + fr;
    const int bc0 = wc * 32 + fr, bc1 = bc0 + 16;

    for (int it = 0; it < 16; ++it) {
        const int db = it & 1;
        if (it < 15) stage(it + 1, db ^ 1);
        const ushort* tb = &lds[team][db][0];
        #pragma unroll
        for (int ks = 0; ks < 2; ++ks) {
            const int kb = (ks * 32 + (lane >> 4) * 8) ^ swz;
            const short8 ah  = *(const short8*)&tb[       arow * 64 + kb];
            const short8 al  = *(const short8*)&tb[2048 + arow * 64 + kb];
            const short8 bh0 = *(const short8*)&tb[4096 + bc0  * 64 + kb];
            const short8 bh1 = *(const short8*)&tb[4096 + bc1  * 64 + kb];
            const short8 bl0 = *(const short8*)&tb[8192 + bc0  * 64 + kb];
            const short8 bl1 = *(const short8*)&tb[8192 + bc1  * 64 + kb];
            acc0 = __builtin_amdgcn_mfma_f32_16x16x32_bf16(ah, bh0, acc0, 0, 0, 0);
            acc0 = __builtin_amdgcn_mfma_f32_16x16x32_bf16(ah, bl0, acc0, 0, 0, 0);
            acc0 = __builtin_amdgcn_mfma_f32_16x16x32_bf16(al, bh0, acc0, 0, 0, 0);
            acc1 = __builtin_amdgcn_mfma_f32_16x16x32_bf16(ah, bh1, acc1, 0, 0, 0);
            acc1 = __builtin_amdgcn_mfma_f32_16x16x32_bf16(ah, bl1, acc1, 0, 0, 0);
            acc1 = __builtin_amdgcn_mfma_f32_16x16x32_bf16(al, bh1, acc1, 0, 0, 0);
        }
        __syncthreads();
    }

    // cross-team K reduction via LDS (8KB)
    float* red = (float*)&lds[0][0][0];
    if (team == 1) {
        float* p = red + ((size_t)(w4 * 64 + lane)) * 8;
        *(f32x4*)p = acc0;
        *(f32x4*)(p + 4) = acc1;
    }
    __syncthreads();
    if (team == 1) return;
    {
        const float* p = red + ((size_t)(w4 * 64 + lane)) * 8;
        acc0 += *(const f32x4*)p;
        acc1 += *(const f32x4*)(p + 4);
    }

    // epilogue (team 0). C/D: col=lane&15, row=(lane>>4)*4+j
    const int r0 = row0 + wr * 16 + (lane >> 4) * 4;
    const int c0 = col0 + wc * 32 + fr, c1 = c0 + 16;

    if constexpr (NN) {
        const float b0 = bias[c0], b1 = bias[c1];
        float s2[4];
        #pragma unroll
        for (int j = 0; j < 4; ++j) {
            const float h0 = tanhf(acc0[j] + b0);
            const float h1 = tanhf(acc1[j] + b1);
            s2[j] = h0 * h0 + h1 * h1;
            const float p0 = h0 * (1.f - h0 * h0);
            const float p1 = h1 * (1.f - h1 * h1);
            const size_t i0 = (size_t)(r0 + j) * DDIM + c0;
            const size_t i1 = (size_t)(r0 + j) * DDIM + c1;
            const ushort p0h = f2bf(p0); Oh[i0] = p0h; Ol[i0] = f2bf(p0 - bf2f(p0h));
            const ushort p1h = f2bf(p1); Oh[i1] = p1h; Ol[i1] = f2bf(p1 - bf2f(p1h));
        }
        #pragma unroll
        for (int m = 1; m <= 8; m <<= 1)
            #pragma unroll
            for (int j = 0; j < 4; ++j) s2[j] += __shfl_xor(s2[j], m);
        if (fr == 0) {
            #pragma unroll
            for (int j = 0; j < 4; ++j) atomicAdd(&cs_cur[r0 + j], s2[j]);
        }
    } else {
        float mx = 0.f;
        #pragma unroll
        for (int j = 0; j < 4; ++j) {
            const float cf = 5.0f / (sqrtf(cs_cur[r0 + j]) + EPS_);
            #pragma unroll
            for (int n = 0; n < 2; ++n) {
                const float kv = -cf * (n ? acc1[j] : acc0[j]);
                const size_t idx = (size_t)(r0 + j) * DDIM + (n ? c1 : c0);
                if constexpr (MODE == 1) { S[idx] = kv; mx = fmaxf(mx, fabsf(kv)); }
                if constexpr (MODE == 2 || MODE == 3) { S[idx] += 2.f * kv; }
                if constexpr (MODE <= 3) {
                    const float a = xin[idx] + cmul * kv;
                    const ushort ah = f2bf(a);
                    Ash[idx] = ah; Asl[idx] = f2bf(a - bf2f(ah));
                } else {
                    const float xn = xin[idx] + (DT / 6.0f) * (S[idx] + kv);
                    xio[idx] = xn;
                    const ushort ah = f2bf(xn);
                    Ash[idx] = ah; Asl[idx] = f2bf(xn - bf2f(ah));
                }
            }
        }
        if constexpr (MODE == 1) {
            #pragma unroll
            for (int m = 1; m <= 32; m <<= 1) mx = fmaxf(mx, __shfl_xor(mx, m));
            if (lane == 0) atomicMax(maxu, __float_as_uint(mx));
        }
    }
}

__global__ void finalize_k(unsigned* __restrict__ maxu, int* __restrict__ done)
{
    if (!*done) {
        if (__uint_as_float(*maxu) < TOL) *done = 1;
    }
    *maxu = 0u;
}

__global__ __launch_bounds__(256)
void copy_k(const float* __restrict__ src, float* __restrict__ dst)
{
    const size_t i = ((size_t)blockIdx.x * 256 + threadIdx.x) * 4;
    *(float4*)&dst[i] = *(const float4*)&src[i];
}

// ===========================================================================
extern "C" void kernel_launch(void* const* d_in, const int* in_sizes, int n_in,
                              void* d_out, int out_size, void* d_ws, size_t ws_size,
                              hipStream_t stream)
{
    const float* x0   = (const float*)d_in[0];
    const float* W    = (const float*)d_in[1];
    const float* bias = (const float*)d_in[2];
    float* out = (float*)d_out;

    const size_t NE = (size_t)BDIM * DDIM;   // 524288
    const size_t M4 = (size_t)DDIM * DDIM;   // 4194304

    // ws layout (floats then ushorts); total ~40.0 MB (< proven 44 MB ws)
    float* ws = (float*)d_ws;
    float* x    = ws;                        // NE
    float* S    = ws + NE;                   // NE
    float* csum = ws + 2 * NE;               // 1024 (4 stage buffers x 256)
    unsigned* maxu = (unsigned*)(csum + 1024);
    int*      done = (int*)(maxu + 1);
    ushort* us = (ushort*)(ws + 2 * NE + 1032);   // 16B-aligned
    ushort* Ash = us;                // NE: A-side (x + c*k) hi
    ushort* Asl = us + NE;           // NE
    ushort* Ph  = us + 2 * NE;       // NE: p = h(1-h^2) hi
    ushort* Pl  = us + 3 * NE;       // NE
    ushort* Wth = us + 4 * NE;       // M4: W^T hi (NN B)
    ushort* Wtl = Wth + M4;          // M4
    ushort* Wh  = Wth + 2 * M4;      // M4: W hi (NT B)
    ushort* Wl  = Wth + 3 * M4;      // M4

    prep_w_k <<<4096, 256, 0, stream>>>(W, Wh, Wl);
    prep_wt_k<<<dim3(32, 32), 256, 0, stream>>>(W, Wth, Wtl);
    init3_k  <<<512, 256, 0, stream>>>(x0, x, Ash, Asl, csum, maxu, done);

    const dim3 gG(DDIM / 64, BDIM / 32);     // (32, 8) = 256 blocks
    float* cs0 = csum, *cs1 = csum + 256, *cs2 = csum + 512, *cs3 = csum + 768;

    for (int s = 0; s < NSTEP; ++s) {
        // k1 = pvf(x): NN then NT(mode1) + stop condition
        hop3_mm<0><<<gG, 512, 0, stream>>>(Ash, Asl, Wth, Wtl, bias, Ph, Pl,
                                           cs0, nullptr, nullptr, nullptr, nullptr,
                                           nullptr, nullptr, 0.f, nullptr, done);
        hop3_mm<1><<<gG, 512, 0, stream>>>(Ph, Pl, Wh, Wl, nullptr, nullptr, nullptr,
                                           cs0, cs1, x, nullptr, S,
                                           Ash, Asl, 0.5f * DT, maxu, done);
        finalize_k<<<1, 1, 0, stream>>>(maxu, done);
        // k2
        hop3_mm<0><<<gG, 512, 0, stream>>>(Ash, Asl, Wth, Wtl, bias, Ph, Pl,
                                           cs1, nullptr, nullptr, nullptr, nullptr,
                                           nullptr, nullptr, 0.f, nullptr, done);
        hop3_mm<2><<<gG, 512, 0, stream>>>(Ph, Pl, Wh, Wl, nullptr, nullptr, nullptr,
                                           cs1, cs2, x, nullptr, S,
                                           Ash, Asl, 0.5f * DT, nullptr, done);
        // k3
        hop3_mm<0><<<gG, 512, 0, stream>>>(Ash, Asl, Wth, Wtl, bias, Ph, Pl,
                                           cs2, nullptr, nullptr, nullptr, nullptr,
                                           nullptr, nullptr, 0.f, nullptr, done);
        hop3_mm<3><<<gG, 512, 0, stream>>>(Ph, Pl, Wh, Wl, nullptr, nullptr, nullptr,
                                           cs2, cs3, x, nullptr, S,
                                           Ash, Asl, DT, nullptr, done);
        // k4 + RK4 x-update fused
        hop3_mm<0><<<gG, 512, 0, stream>>>(Ash, Asl, Wth, Wtl, bias, Ph, Pl,
                                           cs3, nullptr, nullptr, nullptr, nullptr,
                                           nullptr, nullptr, 0.f, nullptr, done);
        hop3_mm<4><<<gG, 512, 0, stream>>>(Ph, Pl, Wh, Wl, nullptr, nullptr, nullptr,
                                           cs3, cs0, x, x, S,
                                           Ash, Asl, 0.f, nullptr, done);
    }

    copy_k<<<512, 256, 0, stream>>>(x, out);
}

// Round 4
// 12363.319 us; speedup vs baseline: 2.2471x; 2.2471x over previous
//
#include <hip/hip_runtime.h>
#include <math.h>

#define BDIM 256
#define DDIM 2048
constexpr float DT    = 0.1f;
constexpr float TOL   = 0.01f;
constexpr int   NSTEP = 50;      // int(5.0 / 0.1)
constexpr float EPS_  = 1e-8f;

typedef __attribute__((ext_vector_type(8))) short short8;   // 8 bf16 (MFMA A/B frag)
typedef __attribute__((ext_vector_type(4))) float f32x4;    // MFMA C/D frag

__device__ __forceinline__ ushort f2bf(float f) {           // fp32 -> bf16 RNE
    unsigned u = __float_as_uint(f);
    return (ushort)((u + 0x7fffu + ((u >> 16) & 1u)) >> 16);
}
__device__ __forceinline__ float bf2f(ushort h) { return __uint_as_float(((unsigned)h) << 16); }

#define GLOAD_LDS16(g, l) __builtin_amdgcn_global_load_lds( \
    (const __attribute__((address_space(1))) void*)(g),      \
    (__attribute__((address_space(3))) void*)(l), 16, 0, 0)

// ---------------------------------------------------------------------------
// One-time prepack: W -> bf16 hi/lo row-major (NT B operand: W[n][k] k-contig)
// ---------------------------------------------------------------------------
__global__ __launch_bounds__(256)
void prep_w_k(const float* __restrict__ W, ushort* __restrict__ Wh, ushort* __restrict__ Wl)
{
    const size_t i = ((size_t)blockIdx.x * 256 + threadIdx.x) * 4;
    const float4 v = *(const float4*)(W + i);
    ushort4 h, l;
    h.x = f2bf(v.x); l.x = f2bf(v.x - bf2f(h.x));
    h.y = f2bf(v.y); l.y = f2bf(v.y - bf2f(h.y));
    h.z = f2bf(v.z); l.z = f2bf(v.z - bf2f(h.z));
    h.w = f2bf(v.w); l.w = f2bf(v.w - bf2f(h.w));
    *(ushort4*)(Wh + i) = h;
    *(ushort4*)(Wl + i) = l;
}

// One-time prepack: W^T -> bf16 hi/lo (NN B operand: Wt[n][k]=W[k][n] k-contig)
__global__ __launch_bounds__(256)
void prep_wt_k(const float* __restrict__ W, ushort* __restrict__ Wth, ushort* __restrict__ Wtl)
{
    __shared__ float T[64][65];
    const int t = threadIdx.x;
    const int k0 = blockIdx.y * 64, n0 = blockIdx.x * 64;
    const int r = t >> 2, c4 = (t & 3) * 16;
    const float* src = W + (size_t)(k0 + r) * DDIM + n0 + c4;
    #pragma unroll
    for (int j = 0; j < 4; ++j) {
        const float4 v = *(const float4*)(src + j * 4);
        T[r][c4 + j*4 + 0] = v.x; T[r][c4 + j*4 + 1] = v.y;
        T[r][c4 + j*4 + 2] = v.z; T[r][c4 + j*4 + 3] = v.w;
    }
    __syncthreads();
    ushort hb[16], lb[16];
    #pragma unroll
    for (int j = 0; j < 16; ++j) {
        const float v = T[c4 + j][r];
        hb[j] = f2bf(v); lb[j] = f2bf(v - bf2f(hb[j]));
    }
    ushort* oh = Wth + (size_t)(n0 + r) * DDIM + k0 + c4;
    ushort* ol = Wtl + (size_t)(n0 + r) * DDIM + k0 + c4;
    #pragma unroll
    for (int q = 0; q < 4; ++q) {
        *(ushort4*)(oh + q*4) = make_ushort4(hb[q*4], hb[q*4+1], hb[q*4+2], hb[q*4+3]);
        *(ushort4*)(ol + q*4) = make_ushort4(lb[q*4], lb[q*4+1], lb[q*4+2], lb[q*4+3]);
    }
}

// init: x = x0; As = split(x0); zero csum/maxu/done
__global__ __launch_bounds__(256)
void init3_k(const float* __restrict__ x0, float* __restrict__ x,
             ushort* __restrict__ Ash, ushort* __restrict__ Asl,
             float* __restrict__ csum, unsigned* __restrict__ maxu, int* __restrict__ done)
{
    const size_t i = ((size_t)blockIdx.x * 256 + threadIdx.x) * 4;
    const float4 v = *(const float4*)(x0 + i);
    *(float4*)(x + i) = v;
    ushort4 h, l;
    h.x = f2bf(v.x); l.x = f2bf(v.x - bf2f(h.x));
    h.y = f2bf(v.y); l.y = f2bf(v.y - bf2f(h.y));
    h.z = f2bf(v.z); l.z = f2bf(v.z - bf2f(h.z));
    h.w = f2bf(v.w); l.w = f2bf(v.w - bf2f(h.w));
    *(ushort4*)(Ash + i) = h;
    *(ushort4*)(Asl + i) = l;
    if (blockIdx.x == 0) {
        for (int j = threadIdx.x; j < 1024; j += 256) csum[j] = 0.f;
        if (threadIdx.x == 0) { *maxu = 0u; *done = 0; }
    }
}

// ---------------------------------------------------------------------------
// Split-bf16 MFMA GEMM v4. Tile 32x32, BK=64, 256 thr (4 waves, each owns a
// 16x16 C quadrant). Grid (64,8)=512 blocks -> 2 blocks/CU (LDS 32KB).
// Counted-vmcnt 2-phase pipeline (catalog T3 minimum recipe): stage(it+1)
// issued before ds_read+MFMA(it); single vmcnt(0)+s_barrier per K-step.
// All operands pre-split bf16 hi/lo in global; XOR-swizzled LDS (T2, rule 21:
// pre-swizzled DMA source + swizzled ds_read).
// MODE 0: NN  z=A@Wt; epi: h=tanh(z+b), store P=split(h(1-h^2)), csum+=h^2
// MODE 1: NT  kv=-cf*(P@W^T); epi: S=kv, max|kv|, As=split(x+0.5DT*kv)
// MODE 2: NT  epi: S+=2kv, As=split(x+0.5DT*kv)
// MODE 3: NT  epi: S+=2kv, As=split(x+DT*kv)
// MODE 4: NT  epi: x+=DT/6*(S+kv), As=split(x_new)
// NT modes zero cs_next (block 0,0) at kernel end.
// ---------------------------------------------------------------------------
template<int MODE>
__global__ __launch_bounds__(256, 2)
void hop4_mm(const ushort* __restrict__ Ahg, const ushort* __restrict__ Alg,
             const ushort* __restrict__ Bhg, const ushort* __restrict__ Blg,
             const float* __restrict__ bias,
             ushort* __restrict__ Oh, ushort* __restrict__ Ol,
             float* __restrict__ cs_cur, float* __restrict__ cs_next,
             const float* __restrict__ xin, float* __restrict__ xio,
             float* __restrict__ S,
             ushort* __restrict__ Ash, ushort* __restrict__ Asl,
             float cmul, unsigned* __restrict__ maxu, const int* __restrict__ done)
{
    constexpr bool NN = (MODE == 0);
    if (*done) return;

    // [dbuf][Ah|Al|Bh|Bl][32 rows][64 k-shorts] = 32 KB
    __shared__ __align__(16) ushort lds[2][8192];

    const int t = threadIdx.x, lane = t & 63, wid = t >> 6;
    const int wr = wid >> 1, wc = wid & 1;
    const int row0 = blockIdx.y * 32, col0 = blockIdx.x * 32;

    // staging: wave wid owns region wid (0=Ah,1=Al,2=Bh,3=Bl); 4 DMA x 1KB/iter
    const ushort* srcb = (wid == 0) ? Ahg : (wid == 1) ? Alg : (wid == 2) ? Bhg : Blg;
    const int rbase = ((wid < 2) ? row0 : col0) + (lane >> 3);
    const int kk = ((lane & 7) * 8) ^ ((lane >> 3) << 3);   // pre-swizzled source k

    auto stage = [&](int it, int db) {
        const ushort* g = srcb + (size_t)rbase * DDIM + it * 64 + kk;
        #pragma unroll
        for (int j = 0; j < 4; ++j)
            GLOAD_LDS16(g + (size_t)j * 8 * DDIM, &lds[db][wid * 2048 + j * 512]);
    };

    f32x4 acc = {0.f, 0.f, 0.f, 0.f};

    const int fr = lane & 15, kq = (lane >> 4) * 8;
    const int arow = wr * 16 + fr, brow = wc * 16 + fr;
    const int sa = (arow & 7) << 3, sb = (brow & 7) << 3;

    stage(0, 0);
    asm volatile("s_waitcnt vmcnt(0)" ::: "memory");
    __builtin_amdgcn_s_barrier();

    for (int it = 0; it < 32; ++it) {
        const int db = it & 1;
        if (it < 31) stage(it + 1, db ^ 1);    // prefetch: latency hides under MFMA
        const ushort* buf = &lds[db][0];
        #pragma unroll
        for (int ks = 0; ks < 2; ++ks) {
            const int ka = (ks * 32 + kq) ^ sa;
            const int kb = (ks * 32 + kq) ^ sb;
            const short8 ah = *(const short8*)&buf[       arow * 64 + ka];
            const short8 al = *(const short8*)&buf[2048 + arow * 64 + ka];
            const short8 bh = *(const short8*)&buf[4096 + brow * 64 + kb];
            const short8 bl = *(const short8*)&buf[6144 + brow * 64 + kb];
            acc = __builtin_amdgcn_mfma_f32_16x16x32_bf16(ah, bh, acc, 0, 0, 0);
            acc = __builtin_amdgcn_mfma_f32_16x16x32_bf16(ah, bl, acc, 0, 0, 0);
            acc = __builtin_amdgcn_mfma_f32_16x16x32_bf16(al, bh, acc, 0, 0, 0);
        }
        asm volatile("s_waitcnt vmcnt(0) lgkmcnt(0)" ::: "memory");
        __builtin_amdgcn_s_barrier();
    }

    // epilogue. C/D: col=lane&15, row=(lane>>4)*4+j
    const int r0 = row0 + wr * 16 + (lane >> 4) * 4;
    const int c0 = col0 + wc * 16 + fr;

    if constexpr (NN) {
        const float b0 = bias[c0];
        float s2[4];
        #pragma unroll
        for (int j = 0; j < 4; ++j) {
            const float h0 = tanhf(acc[j] + b0);
            s2[j] = h0 * h0;
            const float p0 = h0 * (1.f - h0 * h0);
            const size_t i0 = (size_t)(r0 + j) * DDIM + c0;
            const ushort ph = f2bf(p0);
            Oh[i0] = ph; Ol[i0] = f2bf(p0 - bf2f(ph));
        }
        #pragma unroll
        for (int m = 1; m <= 8; m <<= 1)
            #pragma unroll
            for (int j = 0; j < 4; ++j) s2[j] += __shfl_xor(s2[j], m);
        if (fr == 0) {
            #pragma unroll
            for (int j = 0; j < 4; ++j) atomicAdd(&cs_cur[r0 + j], s2[j]);
        }
    } else {
        float mx = 0.f;
        #pragma unroll
        for (int j = 0; j < 4; ++j) {
            const float cf = 5.0f / (sqrtf(cs_cur[r0 + j]) + EPS_);
            const float kv = -cf * acc[j];
            const size_t idx = (size_t)(r0 + j) * DDIM + c0;
            if constexpr (MODE == 1) { S[idx] = kv; mx = fmaxf(mx, fabsf(kv)); }
            if constexpr (MODE == 2 || MODE == 3) { S[idx] += 2.f * kv; }
            if constexpr (MODE <= 3) {
                const float a = xin[idx] + cmul * kv;
                const ushort ah = f2bf(a);
                Ash[idx] = ah; Asl[idx] = f2bf(a - bf2f(ah));
            } else {
                const float xn = xin[idx] + (DT / 6.0f) * (S[idx] + kv);
                xio[idx] = xn;
                const ushort ah = f2bf(xn);
                Ash[idx] = ah; Asl[idx] = f2bf(xn - bf2f(ah));
            }
        }
        if constexpr (MODE == 1) {
            #pragma unroll
            for (int m = 1; m <= 32; m <<= 1) mx = fmaxf(mx, __shfl_xor(mx, m));
            if (lane == 0) atomicMax(maxu, __float_as_uint(mx));
        }
    }

    if (!NN && blockIdx.x == 0 && blockIdx.y == 0) cs_next[t] = 0.f;
}

__global__ void finalize_k(unsigned* __restrict__ maxu, int* __restrict__ done)
{
    if (!*done) {
        if (__uint_as_float(*maxu) < TOL) *done = 1;
    }
    *maxu = 0u;
}

__global__ __launch_bounds__(256)
void copy_k(const float* __restrict__ src, float* __restrict__ dst)
{
    const size_t i = ((size_t)blockIdx.x * 256 + threadIdx.x) * 4;
    *(float4*)&dst[i] = *(const float4*)&src[i];
}

// ===========================================================================
extern "C" void kernel_launch(void* const* d_in, const int* in_sizes, int n_in,
                              void* d_out, int out_size, void* d_ws, size_t ws_size,
                              hipStream_t stream)
{
    const float* x0   = (const float*)d_in[0];
    const float* W    = (const float*)d_in[1];
    const float* bias = (const float*)d_in[2];
    float* out = (float*)d_out;

    const size_t NE = (size_t)BDIM * DDIM;   // 524288
    const size_t M4 = (size_t)DDIM * DDIM;   // 4194304

    // ws layout (~42 MB, fits proven >=44 MB workspace)
    float* ws = (float*)d_ws;
    float* x    = ws;                        // NE
    float* S    = ws + NE;                   // NE
    float* csum = ws + 2 * NE;               // 1024 (4 stage buffers x 256)
    unsigned* maxu = (unsigned*)(csum + 1024);
    int*      done = (int*)(maxu + 1);
    ushort* us = (ushort*)(ws + 2 * NE + 1032);   // 16B-aligned
    ushort* Ash = us;                // NE: A-side (x + c*k) hi
    ushort* Asl = us + NE;           // NE
    ushort* Ph  = us + 2 * NE;       // NE: p = h(1-h^2) hi
    ushort* Pl  = us + 3 * NE;       // NE
    ushort* Wth = us + 4 * NE;       // M4: W^T hi (NN B)
    ushort* Wtl = Wth + M4;          // M4
    ushort* Wh  = Wth + 2 * M4;      // M4: W hi (NT B)
    ushort* Wl  = Wth + 3 * M4;      // M4

    prep_w_k <<<4096, 256, 0, stream>>>(W, Wh, Wl);
    prep_wt_k<<<dim3(32, 32), 256, 0, stream>>>(W, Wth, Wtl);
    init3_k  <<<512, 256, 0, stream>>>(x0, x, Ash, Asl, csum, maxu, done);

    const dim3 gG(DDIM / 32, BDIM / 32);     // (64, 8) = 512 blocks, 2/CU
    float* cs0 = csum, *cs1 = csum + 256, *cs2 = csum + 512, *cs3 = csum + 768;

    for (int s = 0; s < NSTEP; ++s) {
        // k1 = pvf(x): NN then NT(mode1) + stop condition
        hop4_mm<0><<<gG, 256, 0, stream>>>(Ash, Asl, Wth, Wtl, bias, Ph, Pl,
                                           cs0, nullptr, nullptr, nullptr, nullptr,
                                           nullptr, nullptr, 0.f, nullptr, done);
        hop4_mm<1><<<gG, 256, 0, stream>>>(Ph, Pl, Wh, Wl, nullptr, nullptr, nullptr,
                                           cs0, cs1, x, nullptr, S,
                                           Ash, Asl, 0.5f * DT, maxu, done);
        finalize_k<<<1, 1, 0, stream>>>(maxu, done);
        // k2
        hop4_mm<0><<<gG, 256, 0, stream>>>(Ash, Asl, Wth, Wtl, bias, Ph, Pl,
                                           cs1, nullptr, nullptr, nullptr, nullptr,
                                           nullptr, nullptr, 0.f, nullptr, done);
        hop4_mm<2><<<gG, 256, 0, stream>>>(Ph, Pl, Wh, Wl, nullptr, nullptr, nullptr,
                                           cs1, cs2, x, nullptr, S,
                                           Ash, Asl, 0.5f * DT, nullptr, done);
        // k3
        hop4_mm<0><<<gG, 256, 0, stream>>>(Ash, Asl, Wth, Wtl, bias, Ph, Pl,
                                           cs2, nullptr, nullptr, nullptr, nullptr,
                                           nullptr, nullptr, 0.f, nullptr, done);
        hop4_mm<3><<<gG, 256, 0, stream>>>(Ph, Pl, Wh, Wl, nullptr, nullptr, nullptr,
                                           cs2, cs3, x, nullptr, S,
                                           Ash, Asl, DT, nullptr, done);
        // k4 + RK4 x-update fused
        hop4_mm<0><<<gG, 256, 0, stream>>>(Ash, Asl, Wth, Wtl, bias, Ph, Pl,
                                           cs3, nullptr, nullptr, nullptr, nullptr,
                                           nullptr, nullptr, 0.f, nullptr, done);
        hop4_mm<4><<<gG, 256, 0, stream>>>(Ph, Pl, Wh, Wl, nullptr, nullptr, nullptr,
                                           cs3, cs0, x, x, S,
                                           Ash, Asl, 0.f, nullptr, done);
    }

    copy_k<<<512, 256, 0, stream>>>(x, out);
}